// Round 1
// baseline (630.396 us; speedup 1.0000x reference)
//
#include <hip/hip_runtime.h>

// Dims (from reference): N=100000, E=1600000, D=8, K=1, F=32 everywhere.
#define F 32
#define D 8

// ---------------- transform: xg = x@g ; xr = x@root + b ----------------
__global__ void transform_kernel(const float* __restrict__ x,
                                 const float* __restrict__ g,
                                 const float* __restrict__ root,
                                 const float* __restrict__ b,
                                 float* __restrict__ xg,
                                 float* __restrict__ xr,
                                 int N) {
    __shared__ float gs[F * F];
    __shared__ float rs[F * F];
    for (int i = threadIdx.x; i < F * F; i += blockDim.x) {
        gs[i] = g[i];
        rs[i] = root[i];
    }
    __syncthreads();
    int m = threadIdx.x & 31;
    int node = (int)((blockIdx.x * (size_t)blockDim.x + threadIdx.x) >> 5);
    if (node >= N) return;
    float xv = x[(size_t)node * F + m];          // lane m holds x[node][m]
    int base = threadIdx.x & 32;                 // which half of the wave64
    float accg = 0.f, accr = 0.f;
#pragma unroll
    for (int c = 0; c < F; ++c) {
        float xc = __shfl(xv, base + c, 64);     // broadcast x[node][c]
        accg += xc * gs[c * F + m];
        accr += xc * rs[c * F + m];
    }
    xg[(size_t)node * F + m] = accg;
    xr[(size_t)node * F + m] = accr + b[m];
}

// ---------------- gauss for both layers in one pass over edge_weight ----------------
__global__ void gauss_kernel(const float* __restrict__ ew,
                             const float* __restrict__ mu1, const float* __restrict__ sg1,
                             const float* __restrict__ mu2, const float* __restrict__ sg2,
                             float* __restrict__ gauss1, float* __restrict__ gauss2,
                             int E) {
    int e = blockIdx.x * blockDim.x + threadIdx.x;
    if (e >= E) return;
    const float4* ew4 = (const float4*)(ew + (size_t)e * D);
    float4 w0 = ew4[0], w1 = ew4[1];
    float w[D] = {w0.x, w0.y, w0.z, w0.w, w1.x, w1.y, w1.z, w1.w};
    float s1 = 0.f, s2 = 0.f;
#pragma unroll
    for (int d = 0; d < D; ++d) {
        float d1 = w[d] - mu1[d];
        s1 -= 0.5f * d1 * d1 / (1e-15f + sg1[d] * sg1[d]);
        float d2 = w[d] - mu2[d];
        s2 -= 0.5f * d2 * d2 / (1e-15f + sg2[d] * sg2[d]);
    }
    gauss1[e] = expf(s1);
    gauss2[e] = expf(s2);
}

// ---------------- edge scatter: agg[dst] += xg[src]*gauss ; cnt[dst] += 1 ----------------
__global__ void edge_kernel(const int* __restrict__ ei,      // [2, E] row-major
                            const float* __restrict__ gauss,
                            const float* __restrict__ xg,
                            float* __restrict__ agg,
                            float* __restrict__ cnt,         // nullptr for layer 2
                            int E) {
    long long gid = (long long)blockIdx.x * blockDim.x + threadIdx.x;
    int e = (int)(gid >> 5);
    int m = (int)(gid & 31);
    if (e >= E) return;
    int src = ei[e];
    int dst = ei[E + e];
    float gv = gauss[e];
    float v = xg[(size_t)src * F + m] * gv;
    unsafeAtomicAdd(&agg[(size_t)dst * F + m], v);
    if (cnt != nullptr && m == 0) unsafeAtomicAdd(&cnt[dst], 1.0f);
}

// ---------------- finalize: out = agg/max(cnt,1) + xr ----------------
__global__ void finalize_kernel(const float* __restrict__ agg,
                                const float* __restrict__ cnt,
                                const float* __restrict__ xr,
                                float* __restrict__ out,
                                int N) {
    int gid = blockIdx.x * blockDim.x + threadIdx.x;
    if (gid >= N * F) return;
    int node = gid >> 5;
    float c = cnt[node];
    out[gid] = agg[gid] / fmaxf(c, 1.0f) + xr[gid];
}

extern "C" void kernel_launch(void* const* d_in, const int* in_sizes, int n_in,
                              void* d_out, int out_size, void* d_ws, size_t ws_size,
                              hipStream_t stream) {
    const int*   ei   = (const int*)d_in[0];     // (2, E) int32
    const float* ew   = (const float*)d_in[1];   // (E, 8)
    const float* x    = (const float*)d_in[2];   // (N, 32)
    const float* g1   = (const float*)d_in[3];
    const float* mu1  = (const float*)d_in[4];
    const float* sg1  = (const float*)d_in[5];
    const float* r1   = (const float*)d_in[6];
    const float* b1   = (const float*)d_in[7];
    const float* g2   = (const float*)d_in[8];
    const float* mu2  = (const float*)d_in[9];
    const float* sg2  = (const float*)d_in[10];
    const float* r2   = (const float*)d_in[11];
    const float* b2   = (const float*)d_in[12];
    float* out = (float*)d_out;

    const int E = in_sizes[0] / 2;
    const int N = in_sizes[2] / F;
    const size_t NF = (size_t)N * F;

    float* ws     = (float*)d_ws;
    float* xg     = ws;                 // NF
    float* xr     = ws + NF;            // NF
    float* agg    = ws + 2 * NF;        // NF
    float* h      = ws + 3 * NF;        // NF
    float* cnt    = ws + 4 * NF;        // N
    float* gauss1 = cnt + N;            // E
    float* gauss2 = gauss1 + E;         // E

    const int BT = 256;
    const int blk_node = (int)((NF + BT - 1) / BT);              // N*32 threads
    const int blk_edge = (int)(((size_t)E * 32 + BT - 1) / BT);  // E*32 threads
    const int blk_g    = (E + BT - 1) / BT;

    // zero accumulators (ws is poisoned each call)
    hipMemsetAsync(agg, 0, NF * sizeof(float), stream);
    hipMemsetAsync(cnt, 0, N * sizeof(float), stream);

    // gauss for both layers (one pass over edge_weight)
    gauss_kernel<<<blk_g, BT, 0, stream>>>(ew, mu1, sg1, mu2, sg2, gauss1, gauss2, E);

    // ---- layer 1 ----
    transform_kernel<<<blk_node, BT, 0, stream>>>(x, g1, r1, b1, xg, xr, N);
    edge_kernel<<<blk_edge, BT, 0, stream>>>(ei, gauss1, xg, agg, cnt, E);
    finalize_kernel<<<blk_node, BT, 0, stream>>>(agg, cnt, xr, h, N);

    // ---- layer 2 ----
    hipMemsetAsync(agg, 0, NF * sizeof(float), stream);
    transform_kernel<<<blk_node, BT, 0, stream>>>(h, g2, r2, b2, xg, xr, N);
    edge_kernel<<<blk_edge, BT, 0, stream>>>(ei, gauss2, xg, agg, nullptr, E);
    finalize_kernel<<<blk_node, BT, 0, stream>>>(agg, cnt, xr, out, N);
}

// Round 2
// 519.953 us; speedup vs baseline: 1.2124x; 1.2124x over previous
//
#include <hip/hip_runtime.h>

// Dims (from reference): N=100000, E=1600000, D=8, K=1, F=32 everywhere.
#define F 32
#define D 8
#define SCAN_BLK 256
#define SCAN_ITEMS 4   // 1024 elements per scan block

// ---------------- transform: xg = x@g ; xr = x@root + b ----------------
__global__ void transform_kernel(const float* __restrict__ x,
                                 const float* __restrict__ g,
                                 const float* __restrict__ root,
                                 const float* __restrict__ b,
                                 float* __restrict__ xg,
                                 float* __restrict__ xr,
                                 int N) {
    __shared__ float gs[F * F];
    __shared__ float rs[F * F];
    for (int i = threadIdx.x; i < F * F; i += blockDim.x) {
        gs[i] = g[i];
        rs[i] = root[i];
    }
    __syncthreads();
    int m = threadIdx.x & 31;
    int node = (int)((blockIdx.x * (size_t)blockDim.x + threadIdx.x) >> 5);
    if (node >= N) return;
    float xv = x[(size_t)node * F + m];          // lane m holds x[node][m]
    int base = threadIdx.x & 32;                 // which half of the wave64
    float accg = 0.f, accr = 0.f;
#pragma unroll
    for (int c = 0; c < F; ++c) {
        float xc = __shfl(xv, base + c, 64);     // broadcast x[node][c]
        accg += xc * gs[c * F + m];
        accr += xc * rs[c * F + m];
    }
    xg[(size_t)node * F + m] = accg;
    xr[(size_t)node * F + m] = accr + b[m];
}

// ---------------- degree histogram ----------------
__global__ void degree_kernel(const int* __restrict__ ei, int* __restrict__ deg, int E) {
    int e = blockIdx.x * blockDim.x + threadIdx.x;
    if (e >= E) return;
    atomicAdd(&deg[ei[E + e]], 1);
}

// ---------------- exclusive scan (3-phase) ----------------
__global__ void scan1_kernel(const int* __restrict__ deg, int* __restrict__ off,
                             int* __restrict__ partials, int N) {
    __shared__ int sh[SCAN_BLK];
    int block_base = blockIdx.x * (SCAN_BLK * SCAN_ITEMS);
    int idx = block_base + threadIdx.x * SCAN_ITEMS;
    int v[SCAN_ITEMS];
    int sum = 0;
#pragma unroll
    for (int k = 0; k < SCAN_ITEMS; ++k) {
        v[k] = (idx + k < N) ? deg[idx + k] : 0;
        sum += v[k];
    }
    sh[threadIdx.x] = sum;
    __syncthreads();
    for (int d = 1; d < SCAN_BLK; d <<= 1) {
        int t = (threadIdx.x >= d) ? sh[threadIdx.x - d] : 0;
        __syncthreads();
        sh[threadIdx.x] += t;
        __syncthreads();
    }
    int excl = sh[threadIdx.x] - sum;
    if (threadIdx.x == SCAN_BLK - 1) partials[blockIdx.x] = sh[SCAN_BLK - 1];
    int run = excl;
#pragma unroll
    for (int k = 0; k < SCAN_ITEMS; ++k) {
        if (idx + k < N) off[idx + k] = run;
        run += v[k];
    }
}

__global__ void scan2_kernel(int* __restrict__ partials, int nb) {
    __shared__ int sh[1024];
    int t = threadIdx.x;
    int orig = (t < nb) ? partials[t] : 0;
    sh[t] = orig;
    __syncthreads();
    for (int d = 1; d < 1024; d <<= 1) {
        int v = (t >= d) ? sh[t - d] : 0;
        __syncthreads();
        sh[t] += v;
        __syncthreads();
    }
    if (t < nb) partials[t] = sh[t] - orig;   // exclusive
}

__global__ void scan3_kernel(int* __restrict__ off, int* __restrict__ cursor,
                             const int* __restrict__ partials, int N, int E) {
    int i = blockIdx.x * blockDim.x + threadIdx.x;
    if (i > N) return;
    if (i == N) { off[N] = E; cursor[N] = E; return; }
    int b = i / (SCAN_BLK * SCAN_ITEMS);
    int v = off[i] + partials[b];
    off[i] = v;
    cursor[i] = v;
}

// ---------------- scatter edges into CSR order + fused gauss (both layers) ----------------
__global__ void scatter_kernel(const int* __restrict__ ei, const float* __restrict__ ew,
                               const float* __restrict__ mu1, const float* __restrict__ sg1,
                               const float* __restrict__ mu2, const float* __restrict__ sg2,
                               int* __restrict__ cursor, int* __restrict__ ssorted,
                               float* __restrict__ gs1, float* __restrict__ gs2, int E) {
    int e = blockIdx.x * blockDim.x + threadIdx.x;
    if (e >= E) return;
    int src = ei[e];
    int dst = ei[E + e];
    const float4* ew4 = (const float4*)(ew + (size_t)e * D);
    float4 w0 = ew4[0], w1 = ew4[1];
    float w[D] = {w0.x, w0.y, w0.z, w0.w, w1.x, w1.y, w1.z, w1.w};
    float s1 = 0.f, s2 = 0.f;
#pragma unroll
    for (int d = 0; d < D; ++d) {
        float d1 = w[d] - mu1[d];
        s1 -= 0.5f * d1 * d1 / (1e-15f + sg1[d] * sg1[d]);
        float d2 = w[d] - mu2[d];
        s2 -= 0.5f * d2 * d2 / (1e-15f + sg2[d] * sg2[d]);
    }
    int pos = atomicAdd(&cursor[dst], 1);
    ssorted[pos] = src;
    gs1[pos] = expf(s1);
    gs2[pos] = expf(s2);
}

// ---------------- gather-aggregate + fused finalize ----------------
// one 32-lane group per dst node: out[n] = (1/max(deg,1)) * sum_i xg[src_i]*g_i + xr[n]
__global__ void aggregate_kernel(const int* __restrict__ off,
                                 const int* __restrict__ ssorted,
                                 const float* __restrict__ gs,
                                 const float* __restrict__ xg,
                                 const float* __restrict__ xr,
                                 float* __restrict__ out, int N) {
    int m = threadIdx.x & 31;
    int node = (int)((blockIdx.x * (size_t)blockDim.x + threadIdx.x) >> 5);
    if (node >= N) return;
    int base = threadIdx.x & 32;                 // half-wave base for shfl
    int s0 = off[node], s1 = off[node + 1];
    int deg = s1 - s0;
    float acc = 0.f;
    for (int i = s0; i < s1; i += 32) {
        int nchunk = min(32, s1 - i);
        int sv = (i + m < s1) ? ssorted[i + m] : 0;   // coalesced edge meta load
        float gv = (i + m < s1) ? gs[i + m] : 0.f;
        for (int j = 0; j < nchunk; ++j) {
            int s = __shfl(sv, base + j, 64);
            float g = __shfl(gv, base + j, 64);
            acc += xg[(size_t)s * F + m] * g;         // coalesced 128B row gather
        }
    }
    float o = (deg > 0) ? acc / (float)deg : 0.f;
    out[(size_t)node * F + m] = o + xr[(size_t)node * F + m];
}

extern "C" void kernel_launch(void* const* d_in, const int* in_sizes, int n_in,
                              void* d_out, int out_size, void* d_ws, size_t ws_size,
                              hipStream_t stream) {
    const int*   ei   = (const int*)d_in[0];     // (2, E) int32
    const float* ew   = (const float*)d_in[1];   // (E, 8)
    const float* x    = (const float*)d_in[2];   // (N, 32)
    const float* g1   = (const float*)d_in[3];
    const float* mu1  = (const float*)d_in[4];
    const float* sg1  = (const float*)d_in[5];
    const float* r1   = (const float*)d_in[6];
    const float* b1   = (const float*)d_in[7];
    const float* g2   = (const float*)d_in[8];
    const float* mu2  = (const float*)d_in[9];
    const float* sg2  = (const float*)d_in[10];
    const float* r2   = (const float*)d_in[11];
    const float* b2   = (const float*)d_in[12];
    float* out = (float*)d_out;

    const int E = in_sizes[0] / 2;
    const int N = in_sizes[2] / F;
    const size_t NF = (size_t)N * F;

    // workspace layout (all 4-byte elements)
    float* ws      = (float*)d_ws;
    float* xg      = ws;                         // NF
    float* xr      = xg + NF;                    // NF
    float* h       = xr + NF;                    // NF
    float* gs1     = h + NF;                     // E
    float* gs2     = gs1 + E;                    // E
    int*   ssorted = (int*)(gs2 + E);            // E
    int*   deg     = ssorted + E;                // N
    int*   off     = deg + N;                    // N+1
    int*   cursor  = off + N + 1;                // N+1
    int*   partials= cursor + N + 1;             // <=1024

    const int BT = 256;
    const int blk_node = (int)((NF + BT - 1) / BT);       // N*32 threads
    const int blk_edge = (E + BT - 1) / BT;               // E threads
    const int nb_scan  = (N + SCAN_BLK * SCAN_ITEMS - 1) / (SCAN_BLK * SCAN_ITEMS);

    // ---- build dst-CSR (once; shared by both layers) ----
    hipMemsetAsync(deg, 0, N * sizeof(int), stream);
    degree_kernel<<<blk_edge, BT, 0, stream>>>(ei, deg, E);
    scan1_kernel<<<nb_scan, SCAN_BLK, 0, stream>>>(deg, off, partials, N);
    scan2_kernel<<<1, 1024, 0, stream>>>(partials, nb_scan);
    scan3_kernel<<<(N + 1 + BT - 1) / BT, BT, 0, stream>>>(off, cursor, partials, N, E);
    scatter_kernel<<<blk_edge, BT, 0, stream>>>(ei, ew, mu1, sg1, mu2, sg2,
                                                cursor, ssorted, gs1, gs2, E);

    // ---- layer 1 ----
    transform_kernel<<<blk_node, BT, 0, stream>>>(x, g1, r1, b1, xg, xr, N);
    aggregate_kernel<<<blk_node, BT, 0, stream>>>(off, ssorted, gs1, xg, xr, h, N);

    // ---- layer 2 ----
    transform_kernel<<<blk_node, BT, 0, stream>>>(h, g2, r2, b2, xg, xr, N);
    aggregate_kernel<<<blk_node, BT, 0, stream>>>(off, ssorted, gs2, xg, xr, out, N);
}

// Round 4
// 464.868 us; speedup vs baseline: 1.3561x; 1.1185x over previous
//
#include <hip/hip_runtime.h>

// Dims (from reference): N=100000, E=1600000, D=8, K=1, F=32 everywhere.
#define F 32
#define D 8
#define SCAN_BLK 256
#define SCAN_ITEMS 4   // 1024 elements per scan block

typedef int iv4 __attribute__((ext_vector_type(4)));   // native vec for nt-store

// ---------------- transform: xg = x@g ; xr = x@root + b ----------------
__global__ void transform_kernel(const float* __restrict__ x,
                                 const float* __restrict__ g,
                                 const float* __restrict__ root,
                                 const float* __restrict__ b,
                                 float* __restrict__ xg,
                                 float* __restrict__ xr,
                                 int N) {
    __shared__ float gs[F * F];
    __shared__ float rs[F * F];
    for (int i = threadIdx.x; i < F * F; i += blockDim.x) {
        gs[i] = g[i];
        rs[i] = root[i];
    }
    __syncthreads();
    int m = threadIdx.x & 31;
    int node = (int)((blockIdx.x * (size_t)blockDim.x + threadIdx.x) >> 5);
    if (node >= N) return;
    float xv = x[(size_t)node * F + m];          // lane m holds x[node][m]
    int base = threadIdx.x & 32;                 // which half of the wave64
    float accg = 0.f, accr = 0.f;
#pragma unroll
    for (int c = 0; c < F; ++c) {
        float xc = __shfl(xv, base + c, 64);     // broadcast x[node][c]
        accg += xc * gs[c * F + m];
        accr += xc * rs[c * F + m];
    }
    xg[(size_t)node * F + m] = accg;
    xr[(size_t)node * F + m] = accr + b[m];
}

// ---------------- degree histogram ----------------
__global__ void degree_kernel(const int* __restrict__ ei, int* __restrict__ deg, int E) {
    int e = blockIdx.x * blockDim.x + threadIdx.x;
    if (e >= E) return;
    atomicAdd(&deg[ei[E + e]], 1);
}

// ---------------- exclusive scan (3-phase) ----------------
__global__ void scan1_kernel(const int* __restrict__ deg, int* __restrict__ off,
                             int* __restrict__ partials, int N) {
    __shared__ int sh[SCAN_BLK];
    int block_base = blockIdx.x * (SCAN_BLK * SCAN_ITEMS);
    int idx = block_base + threadIdx.x * SCAN_ITEMS;
    int v[SCAN_ITEMS];
    int sum = 0;
#pragma unroll
    for (int k = 0; k < SCAN_ITEMS; ++k) {
        v[k] = (idx + k < N) ? deg[idx + k] : 0;
        sum += v[k];
    }
    sh[threadIdx.x] = sum;
    __syncthreads();
    for (int d = 1; d < SCAN_BLK; d <<= 1) {
        int t = (threadIdx.x >= d) ? sh[threadIdx.x - d] : 0;
        __syncthreads();
        sh[threadIdx.x] += t;
        __syncthreads();
    }
    int excl = sh[threadIdx.x] - sum;
    if (threadIdx.x == SCAN_BLK - 1) partials[blockIdx.x] = sh[SCAN_BLK - 1];
    int run = excl;
#pragma unroll
    for (int k = 0; k < SCAN_ITEMS; ++k) {
        if (idx + k < N) off[idx + k] = run;
        run += v[k];
    }
}

__global__ void scan2_kernel(int* __restrict__ partials, int nb) {
    __shared__ int sh[1024];
    int t = threadIdx.x;
    int orig = (t < nb) ? partials[t] : 0;
    sh[t] = orig;
    __syncthreads();
    for (int d = 1; d < 1024; d <<= 1) {
        int v = (t >= d) ? sh[t - d] : 0;
        __syncthreads();
        sh[t] += v;
        __syncthreads();
    }
    if (t < nb) partials[t] = sh[t] - orig;   // exclusive
}

__global__ void scan3_kernel(int* __restrict__ off, int* __restrict__ cursor,
                             const int* __restrict__ partials, int N, int E) {
    int i = blockIdx.x * blockDim.x + threadIdx.x;
    if (i > N) return;
    if (i == N) { off[N] = E; cursor[N] = E; return; }
    int b = i / (SCAN_BLK * SCAN_ITEMS);
    int v = off[i] + partials[b];
    off[i] = v;
    cursor[i] = v;
}

// ---------------- scatter edges into CSR order, packed payload ----------------
// edata[pos] = (src, bits(gauss1), bits(gauss2), 0) — ONE 16B nt store per edge
__global__ void scatter_kernel(const int* __restrict__ ei, const float* __restrict__ ew,
                               const float* __restrict__ mu1, const float* __restrict__ sg1,
                               const float* __restrict__ mu2, const float* __restrict__ sg2,
                               int* __restrict__ cursor, iv4* __restrict__ edata, int E) {
    int e = blockIdx.x * blockDim.x + threadIdx.x;
    if (e >= E) return;
    int src = ei[e];
    int dst = ei[E + e];
    const float4* ew4 = (const float4*)(ew + (size_t)e * D);
    float4 w0 = ew4[0], w1 = ew4[1];
    float w[D] = {w0.x, w0.y, w0.z, w0.w, w1.x, w1.y, w1.z, w1.w};
    float s1 = 0.f, s2 = 0.f;
#pragma unroll
    for (int d = 0; d < D; ++d) {
        float d1 = w[d] - mu1[d];
        s1 -= 0.5f * d1 * d1 / (1e-15f + sg1[d] * sg1[d]);
        float d2 = w[d] - mu2[d];
        s2 -= 0.5f * d2 * d2 / (1e-15f + sg2[d] * sg2[d]);
    }
    int pos = atomicAdd(&cursor[dst], 1);
    iv4 payload;
    payload.x = src;
    payload.y = __float_as_int(expf(s1));
    payload.z = __float_as_int(expf(s2));
    payload.w = 0;
    __builtin_nontemporal_store(payload, &edata[pos]);
}

// ---------------- gather-aggregate + fused finalize ----------------
// one 32-lane group per dst node: out[n] = (1/max(deg,1)) * sum_i xg[src_i]*g_i + xr[n]
template <int WHICH>
__global__ void aggregate_kernel(const int* __restrict__ off,
                                 const iv4* __restrict__ edata,
                                 const float* __restrict__ xg,
                                 const float* __restrict__ xr,
                                 float* __restrict__ out, int N) {
    int m = threadIdx.x & 31;
    int node = (int)((blockIdx.x * (size_t)blockDim.x + threadIdx.x) >> 5);
    if (node >= N) return;
    int base = threadIdx.x & 32;                 // half-wave base for shfl
    int s0 = off[node], s1 = off[node + 1];
    int deg = s1 - s0;
    float acc = 0.f;
    for (int i = s0; i < s1; i += 32) {
        int nchunk = min(32, s1 - i);
        int sv = 0;
        float gv = 0.f;
        if (i + m < s1) {
            iv4 ed = edata[i + m];               // coalesced 16B load
            sv = ed.x;
            gv = __int_as_float(WHICH == 1 ? ed.y : ed.z);
        }
        for (int j = 0; j < nchunk; ++j) {
            int s = __shfl(sv, base + j, 64);
            float g = __shfl(gv, base + j, 64);
            acc += xg[(size_t)s * F + m] * g;    // coalesced 128B row gather
        }
    }
    float o = (deg > 0) ? acc / (float)deg : 0.f;
    out[(size_t)node * F + m] = o + xr[(size_t)node * F + m];
}

extern "C" void kernel_launch(void* const* d_in, const int* in_sizes, int n_in,
                              void* d_out, int out_size, void* d_ws, size_t ws_size,
                              hipStream_t stream) {
    const int*   ei   = (const int*)d_in[0];     // (2, E) int32
    const float* ew   = (const float*)d_in[1];   // (E, 8)
    const float* x    = (const float*)d_in[2];   // (N, 32)
    const float* g1   = (const float*)d_in[3];
    const float* mu1  = (const float*)d_in[4];
    const float* sg1  = (const float*)d_in[5];
    const float* r1   = (const float*)d_in[6];
    const float* b1   = (const float*)d_in[7];
    const float* g2   = (const float*)d_in[8];
    const float* mu2  = (const float*)d_in[9];
    const float* sg2  = (const float*)d_in[10];
    const float* r2   = (const float*)d_in[11];
    const float* b2   = (const float*)d_in[12];
    float* out = (float*)d_out;

    const int E = in_sizes[0] / 2;
    const int N = in_sizes[2] / F;
    const size_t NF = (size_t)N * F;

    // workspace layout (16B-aligned edata first)
    iv4*   edata   = (iv4*)d_ws;                 // E * 16B
    float* xg      = (float*)(edata + E);        // NF
    float* xr      = xg + NF;                    // NF
    int*   deg     = (int*)(xr + NF);            // N
    int*   off     = deg + N;                    // N+1
    int*   cursor  = off + N + 1;                // N+1
    int*   partials= cursor + N + 1;             // <=1024
    float* h       = out;                        // layer-1 output lives in d_out

    const int BT = 256;
    const int blk_node = (int)((NF + BT - 1) / BT);       // N*32 threads
    const int blk_edge = (E + BT - 1) / BT;               // E threads
    const int nb_scan  = (N + SCAN_BLK * SCAN_ITEMS - 1) / (SCAN_BLK * SCAN_ITEMS);

    // ---- build dst-CSR (once; shared by both layers) ----
    (void)hipMemsetAsync(deg, 0, N * sizeof(int), stream);
    degree_kernel<<<blk_edge, BT, 0, stream>>>(ei, deg, E);
    scan1_kernel<<<nb_scan, SCAN_BLK, 0, stream>>>(deg, off, partials, N);
    scan2_kernel<<<1, 1024, 0, stream>>>(partials, nb_scan);
    scan3_kernel<<<(N + 1 + BT - 1) / BT, BT, 0, stream>>>(off, cursor, partials, N, E);
    scatter_kernel<<<blk_edge, BT, 0, stream>>>(ei, ew, mu1, sg1, mu2, sg2,
                                                cursor, edata, E);

    // ---- layer 1 ----
    transform_kernel<<<blk_node, BT, 0, stream>>>(x, g1, r1, b1, xg, xr, N);
    aggregate_kernel<1><<<blk_node, BT, 0, stream>>>(off, edata, xg, xr, h, N);

    // ---- layer 2 ----
    transform_kernel<<<blk_node, BT, 0, stream>>>(h, g2, r2, b2, xg, xr, N);
    aggregate_kernel<2><<<blk_node, BT, 0, stream>>>(off, edata, xg, xr, out, N);
}